// Round 10
// baseline (131.575 us; speedup 1.0000x reference)
//
#include <hip/hip_runtime.h>
#include <hip/hip_bf16.h>

// B=8, T=2048, C=1024, H=64 single-head causal attention. f32 in, f32 out.
// Round 19: qkv column-chunk pipeline. R9 left qkv as serial stage(10.2us
// HBM floor) + compute(~10us) at 1 block/CU. Now the 64x1024 input is staged
// in 4 COLUMN chunks (256 f32 = 8 kci each, 32KB LDS, 2 buffers = 64KB):
// compute chunk c (8 kci x 4 row-groups) runs while chunk c+1's HBM loads
// fly (issue -> sched_barrier -> MFMAs -> LDS write -> barrier). The wf ring
// walks kci monotonically ACROSS chunks, so Wp is still read exactly once
// per CU (384 KB contiguous — R7's double-read bug structurally impossible).
// Expected qkv ~= stage floor (~12-14us). attn/transpose_w unchanged from
// R18 (best, 130.1us). fillBufferAligned (2x ~41us, 268MB ws-poison) is
// unconditional harness overhead — fixed floor.
// Region map: region rt (0..1023) = 16 tokens, stride regsz bf16.
// Q[t][h]@0, K packed@1024 (2 half-frags), V^T[h][t16]@2048.

typedef __bf16 bf16;
typedef __bf16 bf16x8 __attribute__((ext_vector_type(8)));
typedef float f32x4 __attribute__((ext_vector_type(4)));
typedef unsigned int u32;
typedef u32 u32x2 __attribute__((ext_vector_type(2)));
typedef u32 u32x4 __attribute__((ext_vector_type(4)));

#define T_SZ 2048
#define C_SZ 1024
#define H_SZ 64
#define QOFF 0
#define KOFF 1024
#define VOFF 2048
#define PPITCH 72
#define NEG_BIG (-30000.0f)
#define QSCALE 0.04508422f  // (1/32) * log2(e)

__device__ __forceinline__ bf16x8 ld8(const bf16* p) { return *(const bf16x8*)p; }

// DPP rotate within 16-lane row. ROW_ROR:n = 0x120|n.
template <int CTRL>
__device__ __forceinline__ float dpp_mov(float x) {
  return __builtin_bit_cast(float,
      __builtin_amdgcn_update_dpp(0, __builtin_bit_cast(int, x), CTRL, 0xf, 0xf, true));
}
__device__ __forceinline__ float qmax16(float x) {
  x = fmaxf(x, dpp_mov<0x121>(x));
  x = fmaxf(x, dpp_mov<0x122>(x));
  x = fmaxf(x, dpp_mov<0x124>(x));
  x = fmaxf(x, dpp_mov<0x128>(x));
  return x;
}
__device__ __forceinline__ float qsum16(float x) {
  x += dpp_mov<0x121>(x);
  x += dpp_mov<0x122>(x);
  x += dpp_mov<0x124>(x);
  x += dpp_mov<0x128>(x);
  return x;
}

// ---------------------------------------------------------------------------
// Fragment-packed weights: Wp elem[(jj*32+kci)*512 + l15*32 + quad*8 + e] =
// W[c = kci*32+quad*8+e][h = (jj&3)*16+l15] of matrix jj>>2 (0=Q,1=K,2=V).
// QSCALE folded into Wq. Thread (r=h, cb) covers c = ct*64+cb .. +15.
__global__ __launch_bounds__(256) void transpose_w(const float* __restrict__ Wq,
                                                   const float* __restrict__ Wk,
                                                   const float* __restrict__ Wv,
                                                   bf16* __restrict__ Wp) {
  __shared__ float sh[64][65];
  int ct = blockIdx.x;
  int mat = blockIdx.y;
  const float* W = (mat == 0) ? Wq : (mat == 1 ? Wk : Wv);
  int tid = threadIdx.x;
  int r = tid >> 2, cb = (tid & 3) * 16;

  const f32x4* src = (const f32x4*)(W + (size_t)(ct * 64 + r) * H_SZ + cb);
#pragma unroll
  for (int v = 0; v < 4; ++v) {
    f32x4 x = src[v];
#pragma unroll
    for (int jx = 0; jx < 4; ++jx) sh[r][cb + v * 4 + jx] = x[jx];
  }
  __syncthreads();

  float scale = (mat == 0) ? QSCALE : 1.0f;
  bf16x8 o0, o1;
#pragma unroll
  for (int jx = 0; jx < 8; ++jx) o0[jx] = (bf16)(sh[cb + jx][r] * scale);
#pragma unroll
  for (int jx = 0; jx < 8; ++jx) o1[jx] = (bf16)(sh[cb + 8 + jx][r] * scale);

  int jj = mat * 4 + (r >> 4);       // fragment-col 0..11
  int l15 = r & 15;
  int c0 = ct * 64 + cb;
  int kci = c0 >> 5;
  int qa = (c0 >> 3) & 3;            // first quad of the 16-elem span
  bf16* dst = Wp + (size_t)(jj * 32 + kci) * 512 + l15 * 32 + qa * 8;
  *(bf16x8*)dst = o0;        // quad qa   (8 elems)
  *(bf16x8*)(dst + 8) = o1;  // quad qa+1 (8 elems)
}

// ---------------------------------------------------------------------------
// QKV: 256 blocks x 768 thr (12 waves), 1 block/CU, M=64 tokens.
// Wave j (0..11) owns ONE 16-col fragment (j<4 Q, j<8 K, else V), 4 MFMAs
// (row-groups) per kci. Wp traffic 384 KB/CU, every wf load contiguous 1KB.
// Column-chunk pipeline: chunk c = cols [c*256,(c+1)*256) f32 = kci 8c..8c+7.
// LDS = 2 x 32KB buffers, layout [kci_local][row][quad] (1024B-contiguous
// conflict-free df reads, row*64 = rg*1024 + l15*64). Per chunk: issue next
// chunk's 6 guarded nontemporal loads -> sched_barrier -> 8 kci x 4 rg MFMA
// -> write next chunk to other buffer -> barrier. wf ring monotone in kci
// across chunks -> Wp read once.
//   Q/K: mfma(wf, df) -> D[h][t];  V: mfma(df, wf) -> D[t][h].
// K epilogue stores in half-fragment order for attn's contiguous kf loads.
__global__ __launch_bounds__(768, 3) void qkv(const float* data, const bf16* __restrict__ Wp,
                                              bf16* arena, int regsz) {
  __shared__ bf16 As[2 * 16384];  // 2 x 32 KiB chunk buffers
  char* As_b = (char*)As;
  int blk = blockIdx.x;
  int tid = threadIdx.x;
  int w = tid >> 6, lane = tid & 63;
  int l15 = lane & 15, quad = lane >> 4;

  const float* src = data + (size_t)blk * 64 * C_SZ;

  // ---- stage chunk 0 (cols 0..255 f32) into buffer 0 ----------------------
  f32x4 st[6];
#pragma unroll
  for (int i = 0; i < 6; ++i) {
    if (i < 5 || tid < 256) {  // 4096 units = 5*768 + 256
      int v = i * 768 + tid;
      int row = v >> 6, c4l = v & 63;
      st[i] = __builtin_nontemporal_load(
          (const f32x4*)(src + (size_t)row * C_SZ + c4l * 4));
    }
  }
#pragma unroll
  for (int i = 0; i < 6; ++i) {
    if (i < 5 || tid < 256) {
      int v = i * 768 + tid;
      int row = v >> 6, c4l = v & 63;
      bf16 t4[4] = {(bf16)st[i][0], (bf16)st[i][1], (bf16)st[i][2], (bf16)st[i][3]};
      int bo = ((c4l >> 3) << 12) + row * 64 + (c4l & 7) * 8;
      *(u32x2*)(As_b + bo) = *(const u32x2*)t4;
    }
  }
  __syncthreads();

  // ---- compute setup: wave w owns fragment-col j = w ----------------------
  int j = w;
  const bf16* wb = Wp + (size_t)j * 32 * 512 + l15 * 32 + quad * 8;  // kci stride 512
  bf16x8 wf[2];
  wf[0] = ld8(wb);        // kci 0
  wf[1] = ld8(wb + 512);  // kci 1

  f32x4 acc[4];
  f32x4 zero = {0.f, 0.f, 0.f, 0.f};
#pragma unroll
  for (int rg = 0; rg < 4; ++rg) acc[rg] = zero;

  bool isQK = (j < 8);
  int lbase = l15 * 64 + quad * 16;  // lane offset within a 1024B (kci,rg) slab

#pragma unroll
  for (int c = 0; c < 4; ++c) {
    // issue chunk c+1 HBM loads (fly under this chunk's compute)
    if (c < 3) {
#pragma unroll
      for (int i = 0; i < 6; ++i) {
        if (i < 5 || tid < 256) {
          int v = i * 768 + tid;
          int row = v >> 6, c4l = v & 63;
          st[i] = __builtin_nontemporal_load(
              (const f32x4*)(src + (size_t)row * C_SZ + ((c + 1) * 64 + c4l) * 4));
        }
      }
      __builtin_amdgcn_sched_barrier(0);  // pin load issue before compute
    }

    int rb = (c & 1) * 32768;
#pragma unroll
    for (int kl = 0; kl < 8; ++kl) {
      int kci = c * 8 + kl;
      int cur = kci & 1;  // compile-time (c,kl static)
      bf16x8 df[4];
#pragma unroll
      for (int rg = 0; rg < 4; ++rg)
        df[rg] = ld8((const bf16*)(As_b + rb + (kl << 12) + rg * 1024 + lbase));
      if (isQK) {
#pragma unroll
        for (int rg = 0; rg < 4; ++rg)
          acc[rg] = __builtin_amdgcn_mfma_f32_16x16x32_bf16(wf[cur], df[rg], acc[rg], 0, 0, 0);
      } else {
#pragma unroll
        for (int rg = 0; rg < 4; ++rg)
          acc[rg] = __builtin_amdgcn_mfma_f32_16x16x32_bf16(df[rg], wf[cur], acc[rg], 0, 0, 0);
      }
      wf[cur] = ld8(wb + ((kci + 2) & 31) * 512);  // monotone ring (wrap-safe)
    }

    // write chunk c+1 into the other buffer
    if (c < 3) {
      int wbuf = ((c + 1) & 1) * 32768;
#pragma unroll
      for (int i = 0; i < 6; ++i) {
        if (i < 5 || tid < 256) {
          int v = i * 768 + tid;
          int row = v >> 6, c4l = v & 63;
          bf16 t4[4] = {(bf16)st[i][0], (bf16)st[i][1], (bf16)st[i][2], (bf16)st[i][3]};
          int bo = wbuf + ((c4l >> 3) << 12) + row * 64 + (c4l & 7) * 8;
          *(u32x2*)(As_b + bo) = *(const u32x2*)t4;
        }
      }
    }
    __syncthreads();
  }

  // ---- epilogue: packed 8B stores into 4 sub-regions ----------------------
#pragma unroll
  for (int rg = 0; rg < 4; ++rg) {
    bf16* reg = arena + (size_t)(blk * 4 + rg) * (size_t)regsz;
    bf16 p4[4] = {(bf16)acc[rg][0], (bf16)acc[rg][1], (bf16)acc[rg][2], (bf16)acc[rg][3]};
    if (j < 4) {         // Q: [t][h], t=l15, h = j*16 + quad*4 + r
      bf16* dst = reg + QOFF + l15 * 64 + j * 16 + quad * 4;
      *(u32x2*)dst = *(const u32x2*)p4;
    } else if (j < 8) {  // K: half-fragment order, h = (j-4)*16 + quad*4 + r
      int jk = j - 4;
      bf16* dst = reg + KOFF + (jk >> 1) * 512 + l15 * 32 + (jk & 1) * 16 + quad * 4;
      *(u32x2*)dst = *(const u32x2*)p4;
    } else {             // V: D[t][h] -> V^T[h][t16], h = (j-8)*16 + l15
      bf16* dst = reg + VOFF + ((j - 8) * 16 + l15) * 16 + quad * 4;
      *(u32x2*)dst = *(const u32x2*)p4;
    }
  }
}

// ---------------------------------------------------------------------------
// Flash attention. Block = one (qt, slice, b) 16x64 output tile; 4 waves each
// own a QUARTER of kt in [0, qt], private (m,l,accO); one LDS merge at end.
// Grid 1024 1-D: b = id&7 (pins batch b to XCD b), t = id>>3, slice = t&3,
// qt = 31-(t>>2) (LPT order). 4 blocks/CU -> 16 waves/CU.
// K is stored in half-fragment order: kf loads are contiguous 1KB blocks.
__global__ __launch_bounds__(256, 4) void attn(const bf16* __restrict__ arena,
                                               float* __restrict__ out, int regsz) {
  __shared__ bf16 Ps[4][16 * PPITCH];
  __shared__ f32x4 Mg[3][6][64];  // waves 1..3 dump {accO[0..3], m, l}
  int id = blockIdx.x;
  int b = id & 7;
  int t = id >> 3;
  int slice = t & 3;
  int qt = 31 - (t >> 2);
  int tid = threadIdx.x;
  int w = tid >> 6, lane = tid & 63;
  int l15 = lane & 15, quad = lane >> 4;

  const bf16* base = arena + (size_t)b * 128 * (size_t)regsz;

  const bf16* qreg = base + (size_t)(qt * 4 + slice) * (size_t)regsz + QOFF + l15 * 64;
  bf16x8 qf0 = ld8(qreg + quad * 8);
  bf16x8 qf1 = ld8(qreg + 32 + quad * 8);

  f32x4 accO[4];
  f32x4 zero = {0.f, 0.f, 0.f, 0.f};
#pragma unroll
  for (int nt = 0; nt < 4; ++nt) accO[nt] = zero;
  float m[4], l[4];
#pragma unroll
  for (int r = 0; r < 4; ++r) { m[r] = NEG_BIG; l[r] = 0.f; }

  int qrow_base = qt * 64 + slice * 16 + quad * 4;
  int vro = (quad >> 1);                 // V region sub-index
  int vco = (quad & 1) * 8;              // V in-row offset

  // this wave's kt quarter
  int q4 = (qt + 4) >> 2;                // ceil((qt+1)/4)
  int kbeg = w * q4;
  int kend = min((w + 1) * q4, qt + 1);  // may be empty (kbeg >= kend)

  for (int kt = kbeg; kt < kend; ++kt) {
    // K fragments for this tile (contiguous 1KB half-fragments)
    bf16x8 kf[8];
#pragma unroll
    for (int nt = 0; nt < 4; ++nt) {
      const bf16* kp = base + (size_t)(kt * 4 + nt) * (size_t)regsz + KOFF + l15 * 32 + quad * 8;
      kf[2 * nt] = ld8(kp);            // h 0..31 half
      kf[2 * nt + 1] = ld8(kp + 512);  // h 32..63 half
    }

    f32x4 sA[4];
#pragma unroll
    for (int nt = 0; nt < 4; ++nt) sA[nt] = zero;
#pragma unroll
    for (int nt = 0; nt < 4; ++nt) {
      sA[nt] = __builtin_amdgcn_mfma_f32_16x16x32_bf16(qf0, kf[2 * nt], sA[nt], 0, 0, 0);
      sA[nt] = __builtin_amdgcn_mfma_f32_16x16x32_bf16(qf1, kf[2 * nt + 1], sA[nt], 0, 0, 0);
    }

    // first V half: issue under the softmax (kf regs die at the MFMAs above)
    bf16x8 vf0[4];
#pragma unroll
    for (int nt = 0; nt < 4; ++nt) {
      const bf16* vp = base + (size_t)(kt * 4 + vro) * (size_t)regsz + VOFF +
                       (nt * 16 + l15) * 16 + vco;
      vf0[nt] = ld8(vp);
    }

    if (kt == qt) {  // causal mask on diagonal tile
#pragma unroll
      for (int nt = 0; nt < 4; ++nt) {
        int colg = kt * 64 + nt * 16 + l15;
#pragma unroll
        for (int r = 0; r < 4; ++r)
          if (colg > qrow_base + r) sA[nt][r] = NEG_BIG;
      }
    }

    float alpha[4];
#pragma unroll
    for (int r = 0; r < 4; ++r) {
      float mx = qmax16(fmaxf(fmaxf(sA[0][r], sA[1][r]), fmaxf(sA[2][r], sA[3][r])));
      float mnew = fmaxf(m[r], mx);
      alpha[r] = exp2f(m[r] - mnew);
      m[r] = mnew;
    }

    float rs[4] = {0.f, 0.f, 0.f, 0.f};
#pragma unroll
    for (int nt = 0; nt < 4; ++nt) {
#pragma unroll
      for (int r = 0; r < 4; ++r) {
        float p = exp2f(sA[nt][r] - m[r]);
        sA[nt][r] = p;
        rs[r] += p;
      }
    }
#pragma unroll
    for (int r = 0; r < 4; ++r) l[r] = l[r] * alpha[r] + qsum16(rs[r]);

    // P: C/D layout -> per-wave LDS -> A layout (same-wave RAW, lgkm-ordered)
#pragma unroll
    for (int nt = 0; nt < 4; ++nt) {
#pragma unroll
      for (int r = 0; r < 4; ++r)
        Ps[w][(quad * 4 + r) * PPITCH + nt * 16 + l15] = (bf16)sA[nt][r];
    }

    // second V half: issue before PV so latency hides under first PV block
    bf16x8 vf1[4];
#pragma unroll
    for (int nt = 0; nt < 4; ++nt) {
      const bf16* vp = base + (size_t)(kt * 4 + 2 + vro) * (size_t)regsz + VOFF +
                       (nt * 16 + l15) * 16 + vco;
      vf1[nt] = ld8(vp);
    }

#pragma unroll
    for (int nt = 0; nt < 4; ++nt) {
#pragma unroll
      for (int r = 0; r < 4; ++r) accO[nt][r] *= alpha[r];
    }
    bf16x8 pf0 = ld8((const bf16*)Ps[w] + l15 * PPITCH + quad * 8);
    bf16x8 pf1 = ld8((const bf16*)Ps[w] + l15 * PPITCH + 32 + quad * 8);
#pragma unroll
    for (int nt = 0; nt < 4; ++nt)
      accO[nt] = __builtin_amdgcn_mfma_f32_16x16x32_bf16(pf0, vf0[nt], accO[nt], 0, 0, 0);
#pragma unroll
    for (int nt = 0; nt < 4; ++nt)
      accO[nt] = __builtin_amdgcn_mfma_f32_16x16x32_bf16(pf1, vf1[nt], accO[nt], 0, 0, 0);
  }

  // merge the 4 kt-quarter partials (exact: O* = sum_w O_w * 2^(m_w - m*))
  if (w > 0) {
#pragma unroll
    for (int nt = 0; nt < 4; ++nt) Mg[w - 1][nt][lane] = accO[nt];
    f32x4 mv = {m[0], m[1], m[2], m[3]};
    f32x4 lv = {l[0], l[1], l[2], l[3]};
    Mg[w - 1][4][lane] = mv;
    Mg[w - 1][5][lane] = lv;
  }
  __syncthreads();
  if (w == 0) {
#pragma unroll
    for (int wv = 0; wv < 3; ++wv) {
      f32x4 mo = Mg[wv][4][lane];
      f32x4 lo = Mg[wv][5][lane];
      f32x4 oo[4];
#pragma unroll
      for (int nt = 0; nt < 4; ++nt) oo[nt] = Mg[wv][nt][lane];
#pragma unroll
      for (int r = 0; r < 4; ++r) {
        float mnew = fmaxf(m[r], mo[r]);
        float a = exp2f(m[r] - mnew);
        float bs = exp2f(mo[r] - mnew);
        l[r] = l[r] * a + lo[r] * bs;
#pragma unroll
        for (int nt = 0; nt < 4; ++nt) accO[nt][r] = accO[nt][r] * a + oo[nt][r] * bs;
        m[r] = mnew;
      }
    }

    float inv[4];
#pragma unroll
    for (int r = 0; r < 4; ++r) inv[r] = 1.f / l[r];
#pragma unroll
    for (int nt = 0; nt < 4; ++nt) {
#pragma unroll
      for (int r = 0; r < 4; ++r) {
        int tk = qt * 64 + slice * 16 + quad * 4 + r;
        int h = nt * 16 + l15;
        out[((size_t)b * T_SZ + tk) * H_SZ + h] = accO[nt][r] * inv[r];
      }
    }
  }
}

// ---------------------------------------------------------------------------
extern "C" void kernel_launch(void* const* d_in, const int* in_sizes, int n_in,
                              void* d_out, int out_size, void* d_ws, size_t ws_size,
                              hipStream_t stream) {
  const float* data = (const float*)d_in[0];

  // Preferred: arena (1024 regions x 4096 bf16 = 8 MB) + Wp (384 KB) in d_ws.
  // Fallback (tiny ws): alias input (stride 32768) + Wp in d_out. Each M=64
  // qkv block fully consumes its own 256 KB input before writing it.
  const size_t arena_bytes = (size_t)1024 * 4096 * sizeof(bf16);  // 8 MB
  const size_t wt_bytes = (size_t)3 * H_SZ * C_SZ * sizeof(bf16); // 384 KB
  bool ws_ok = (d_ws != nullptr) && (ws_size >= arena_bytes + wt_bytes);

  bf16* arena = ws_ok ? (bf16*)d_ws : (bf16*)d_in[0];
  bf16* Wp = ws_ok ? (bf16*)((char*)d_ws + arena_bytes) : (bf16*)d_out;
  int regsz = ws_ok ? 4096 : 32768;

  transpose_w<<<dim3(16, 3), 256, 0, stream>>>((const float*)d_in[1],
                                               (const float*)d_in[2],
                                               (const float*)d_in[3], Wp);
  qkv<<<256, 768, 0, stream>>>(data, Wp, arena, regsz);
  attn<<<1024, 256, 0, stream>>>(arena, (float*)d_out, regsz);
}